// Round 17
// baseline (195.843 us; speedup 1.0000x reference)
//
#include <hip/hip_runtime.h>
#include <hip/hip_fp16.h>
#include <stdint.h>

// Problem constants (fixed by setup_inputs)
#define TT 2048
#define BB 64
#define VV 256
#define SS 256
#define LL 513
#define WPB 8          // waves per block; 2 waves per SIMD (4 SIMDs/CU)

#define F_L2E 1.4426950408889634f
#define F_LN2 0.6931471805599453f
#define TGT_E 16   // per-lane rescale target: lane max -> [2^16, 2^17)
#define MARG  40   // max allowed C(i-1)-C(i)
#define KOFF  262144

typedef float f32x2 __attribute__((ext_vector_type(2)));

static __device__ __forceinline__ float exp2_fast(float x) {
  float r; asm("v_exp_f32 %0, %1" : "=v"(r) : "v"(x)); return r;
}
static __device__ __forceinline__ float log2_fast(float x) {
  float r; asm("v_log_f32 %0, %1" : "=v"(r) : "v"(x)); return r;
}
static __device__ __forceinline__ void g2l16(const void* g, void* l) {
  __builtin_amdgcn_global_load_lds((const __attribute__((address_space(1))) void*)g,
                                   (__attribute__((address_space(3))) void*)l, 16, 0, 0);
}
// wave_shr:1 — lane i gets lane i-1's value; lane 0 gets 0 (bound_ctrl). Pure VALU.
static __device__ __forceinline__ float dpp_shr1_f(float x) {
  int r = __builtin_amdgcn_update_dpp(0, __float_as_int(x), 0x138, 0xF, 0xF, true);
  return __int_as_float(r);
}
static __device__ __forceinline__ int dpp_shr1_i(int x) {
  return __builtin_amdgcn_update_dpp(0, x, 0x138, 0xF, 0xF, true);
}
// wave64 inclusive MAX-scan: shr1,2,4,8 (rmask F) + bcast15 (0xa) + bcast31 (0xc)
template <int CTRL, int RMASK>
static __device__ __forceinline__ int dppmax_i(int v) {
  int d = __builtin_amdgcn_update_dpp(v, v, CTRL, RMASK, 0xF, false);
  return v > d ? v : d;
}
static __device__ __forceinline__ int scanmax_i(int v) {
  v = dppmax_i<0x111, 0xF>(v);
  v = dppmax_i<0x112, 0xF>(v);
  v = dppmax_i<0x114, 0xF>(v);
  v = dppmax_i<0x118, 0xF>(v);
  v = dppmax_i<0x142, 0xa>(v);
  v = dppmax_i<0x143, 0xc>(v);
  return v;
}
// 2^d as f32, bit-built: exact for d in [-126,126]; 0 below; clamped above.
static __device__ __forceinline__ float pow2f(int d) {
  int dc = d > 126 ? 126 : d;
  float s = __int_as_float((dc + 127) << 23);
  return (d < -126) ? 0.f : s;
}

// ---------------------------------------------------------------------
// Phase 1: fused exp + row-sum + target-gather. (unchanged, at BW floor)
// ---------------------------------------------------------------------
__global__ __launch_bounds__(256) void k_prep2(const float* __restrict__ lp,
                                               const int* __restrict__ tgt,
                                               __half* __restrict__ Eg,
                                               float* __restrict__ Bl,
                                               float* __restrict__ D2T) {
  __shared__ int tgtl[SS];
  __shared__ __half elds[4][VV];
  int b  = blockIdx.x & (BB - 1);
  int t0 = (blockIdx.x >> 6) << 2;
  int tid = threadIdx.x;
  tgtl[tid] = tgt[b * SS + tid];
  __syncthreads();
  int w = tid >> 6, lane = tid & 63;
  int t = t0 + w;
  float4 x = reinterpret_cast<const float4*>(lp + ((size_t)t * BB + b) * VV)[lane];
  float e0 = exp2_fast(x.x * F_L2E), e1 = exp2_fast(x.y * F_L2E);
  float e2 = exp2_fast(x.z * F_L2E), e3 = exp2_fast(x.w * F_L2E);
  float z = (e0 + e1) + (e2 + e3);
  z += __shfl_xor(z, 1);
  z += __shfl_xor(z, 2);
  z += __shfl_xor(z, 4);
  z += __shfl_xor(z, 8);
  z += __shfl_xor(z, 16);
  z += __shfl_xor(z, 32);
  elds[w][4 * lane + 0] = __float2half_rn(e0);
  elds[w][4 * lane + 1] = __float2half_rn(e1);
  elds[w][4 * lane + 2] = __float2half_rn(e2);
  elds[w][4 * lane + 3] = __float2half_rn(e3);
  asm volatile("s_waitcnt lgkmcnt(0)" ::: "memory");   // wave-local write->read
  int s = 4 * lane;
  union { __half h[4]; uint2 u; } pk;
  pk.h[0] = elds[w][tgtl[s + 0]];
  pk.h[1] = elds[w][tgtl[s + 1]];
  pk.h[2] = elds[w][tgtl[s + 2]];
  pk.h[3] = elds[w][tgtl[s + 3]];
  reinterpret_cast<uint2*>(Eg + ((size_t)b * TT + t) * SS)[lane] = pk.u;
  if (lane == 0) {
    Bl[(size_t)b * TT + t]  = e0;
    D2T[(size_t)b * TT + t] = -log2_fast(z);
  }
}

// ---------------------------------------------------------------------
// Phase 2: f32 CTC DP, packed f32x2 cells (R16 numerics, absmax 0.0).
// This round: 8 waves/block, one batch per wave -> 2 waves co-resident
// per SIMD; hardware interleaving fills the DP chain's dependency
// stalls. Per-wave LDS slices; no cross-wave sync (vmcnt is per-wave).
// ---------------------------------------------------------------------
__global__ __launch_bounds__(512) void k_ctc14(const __half* __restrict__ Eg,
                                               const float* __restrict__ Bl,
                                               const int* __restrict__ tgt,
                                               const int* __restrict__ ilen,
                                               const int* __restrict__ tlen,
                                               const float* __restrict__ D2T,
                                               float* __restrict__ lossw) {
  __shared__ float blanklds[WPB][TT];   // 64 KB
  __shared__ float afin[WPB][LL];       // 16.4 KB
  __shared__ int   cfinl[WPB][64];      // 2 KB
  int tid = threadIdx.x;
  int w = tid >> 6, lane = tid & 63;
  int b = blockIdx.x * WPB + w;
  int len = ilen[b]; if (len > TT) len = TT; if (len < 0) len = 0;
  int tl  = tlen[b]; if (tl > SS) tl = SS; if (tl < 1) tl = 1;

  const float* blb = Bl  + (size_t)b * TT;
  const float* d2b = D2T + (size_t)b * TT;
  const uint2* eq  = reinterpret_cast<const uint2*>(Eg) + (size_t)b * TT * 64 + lane;

  int4 tv = reinterpret_cast<const int4*>(tgt + b * SS)[lane];
  int pw  = __shfl_up(tv.w, 1);
  f32x2 mk13 = { (lane > 0 && tv.x != pw) ? 1.f : 0.f,
                 (tv.y != tv.x) ? 1.f : 0.f };
  f32x2 mk57 = { (tv.z != tv.y) ? 1.f : 0.f,
                 (tv.w != tv.z) ? 1.f : 0.f };

  // stage this wave's blank column (8 KB) into its LDS slice
#pragma unroll
  for (int j = 0; j < 8; ++j)
    g2l16(blb + j * 256 + lane * 4, &blanklds[w][j * 256]);

  uint2 pfA[16], pfB[16], pfC[16];
  // E={a0,a2} O={a1,a3} E2={a4,a6} O2={a5,a7}, a8 scalar
  f32x2 E  = { (lane == 0) ? 1.f : 0.f, 0.f };
  f32x2 O  = { 0.f, 0.f };
  f32x2 E2 = { 0.f, 0.f };
  f32x2 O2 = { 0.f, 0.f };
  float a8 = 0.f;
  int   C = 0;          // per-lane block exponent (log2 units)
  float sc1f = 1.f;     // 2^{C(lane-1)-C(lane)} (bit-built), per rescale

#define ISSUE16(BANK, TBN) do {                                                \
    const uint2* p_ = eq + (size_t)(TBN) * 64;                                 \
    _Pragma("unroll")                                                          \
    for (int j_ = 0; j_ < 16; ++j_) pf##BANK[j_] = p_[(size_t)j_ * 64];        \
  } while (0)

#define STEP32(BANK, J) do {                                                   \
    uint2 pv = pf##BANK[J];                                                    \
    float2 tlo = __half22float2(*reinterpret_cast<const __half2*>(&pv.x));     \
    float2 thi = __half22float2(*reinterpret_cast<const __half2*>(&pv.y));     \
    f32x2 flo = { tlo.x, tlo.y };                                              \
    f32x2 fhi = { thi.x, thi.y };                                              \
    float pb = pbreg[J];                                                       \
    f32x2 pbv = { pb, pb };                                                    \
    float h1 = dpp_shr1_f(O2.y) * sc1f;                                        \
    f32x2 Av = { h1,  O.x  };                                                  \
    f32x2 Bv = { O.y, O2.x };                                                  \
    float a8n  = (a8 + O2.y) * pb;                                             \
    f32x2 En   = (E  + Av) * pbv;                                              \
    f32x2 E2n  = (E2 + Bv) * pbv;                                              \
    f32x2 On   = (O  + E  + mk13 * Av) * flo;                                  \
    f32x2 O2n  = (O2 + E2 + mk57 * Bv) * fhi;                                  \
    E = En; E2 = E2n; O = On; O2 = O2n; a8 = a8n;                              \
  } while (0)

  // Per-lane rescale with margin clamp; packed max-tree; 16-step cadence.
#define RESCALE16() do {                                                       \
    f32x2 m2 = __builtin_elementwise_max(__builtin_elementwise_max(E, O),      \
                                         __builtin_elementwise_max(E2, O2));   \
    float mx = fmaxf(fmaxf(m2.x, m2.y), a8);                                   \
    bool live_ = (mx > 0.f);                                                   \
    int e_  = (int)((__float_as_uint(mx) >> 23) & 0xff);                       \
    int Cl_ = C + e_ - (127 + TGT_E);                                          \
    int key_ = live_ ? (Cl_ + KOFF) : 0;                                       \
    key_ = scanmax_i(key_);                                                    \
    int Cn_ = (key_ - KOFF) - MARG;                                            \
    if (live_ && Cl_ > Cn_) Cn_ = Cl_;                                         \
    int shE_ = Cn_ - C;                                                        \
    E.x  = ldexpf(E.x, -shE_);  E.y  = ldexpf(E.y, -shE_);                     \
    O.x  = ldexpf(O.x, -shE_);  O.y  = ldexpf(O.y, -shE_);                     \
    E2.x = ldexpf(E2.x, -shE_); E2.y = ldexpf(E2.y, -shE_);                    \
    O2.x = ldexpf(O2.x, -shE_); O2.y = ldexpf(O2.y, -shE_);                    \
    a8   = ldexpf(a8, -shE_);                                                  \
    C = Cn_;                                                                   \
    int diffi_ = dpp_shr1_i(C) - C;                                            \
    sc1f = pow2f(diffi_);                                                      \
  } while (0)

#define BLK(CUR, NXT, TB, VMC) do {                                            \
    if ((VMC) == 32) ISSUE16(NXT, (TB) + 32);                                  \
    float pbreg[16];                                                           \
    _Pragma("unroll")                                                          \
    for (int j_ = 0; j_ < 16; ++j_) pbreg[j_] = blanklds[w][(TB) + j_];        \
    asm volatile("s_waitcnt vmcnt(%0)" :: "i"(VMC) : "memory");                \
    STEP32(CUR, 0);  STEP32(CUR, 1);  STEP32(CUR, 2);  STEP32(CUR, 3);         \
    STEP32(CUR, 4);  STEP32(CUR, 5);  STEP32(CUR, 6);  STEP32(CUR, 7);         \
    STEP32(CUR, 8);  STEP32(CUR, 9);  STEP32(CUR, 10); STEP32(CUR, 11);        \
    STEP32(CUR, 12); STEP32(CUR, 13); STEP32(CUR, 14); STEP32(CUR, 15);        \
    RESCALE16();                                                               \
  } while (0)

  int tcur = 0;
  if (len == TT) {
    ISSUE16(A, 0);
    ISSUE16(B, 16);
    for (int g = 0; g < 42; ++g) {
      BLK(A, C, tcur, 32);
      BLK(B, A, tcur + 16, 32);
      BLK(C, B, tcur + 32, 32);
      tcur += 48;
    }
    BLK(A, C, tcur, 16);       // tcur = 2016
    BLK(B, C, tcur + 16, 0);   // 2032
    tcur = TT;
  }

  // generic path (len < TT): plain per-step loads, same numerics
  if (tcur < len) {
    asm volatile("s_waitcnt vmcnt(0)" ::: "memory");
    while (tcur < len) {
      uint2 pv = eq[(size_t)tcur * 64];
      float2 tlo = __half22float2(*reinterpret_cast<const __half2*>(&pv.x));
      float2 thi = __half22float2(*reinterpret_cast<const __half2*>(&pv.y));
      f32x2 flo = { tlo.x, tlo.y };
      f32x2 fhi = { thi.x, thi.y };
      float pb = blanklds[w][tcur];
      f32x2 pbv = { pb, pb };
      float h1 = dpp_shr1_f(O2.y) * sc1f;
      f32x2 Av = { h1,  O.x  };
      f32x2 Bv = { O.y, O2.x };
      float a8n  = (a8 + O2.y) * pb;
      f32x2 En   = (E  + Av) * pbv;
      f32x2 E2n  = (E2 + Bv) * pbv;
      f32x2 On   = (O  + E  + mk13 * Av) * flo;
      f32x2 O2n  = (O2 + E2 + mk57 * Bv) * fhi;
      E = En; E2 = E2n; O = On; O2 = O2n; a8 = a8n;
      ++tcur;
      if ((tcur & 15) == 0) RESCALE16();
    }
  }

  // normalization constant: sum of -log2(Z_t) over t < len
  float dsm = 0.f;
  for (int k2 = 0; k2 < TT / 64; ++k2) {
    int t2 = lane + 64 * k2;
    if (t2 < len) dsm += d2b[t2];
  }
  dsm += __shfl_xor(dsm, 1);
  dsm += __shfl_xor(dsm, 2);
  dsm += __shfl_xor(dsm, 4);
  dsm += __shfl_xor(dsm, 8);
  dsm += __shfl_xor(dsm, 16);
  dsm += __shfl_xor(dsm, 32);

  // cells: a0=E.x a1=O.x a2=E.y a3=O.y a4=E2.x a5=O2.x a6=E2.y a7=O2.y
  afin[w][8 * lane + 0] = E.x;  afin[w][8 * lane + 1] = O.x;
  afin[w][8 * lane + 2] = E.y;  afin[w][8 * lane + 3] = O.y;
  afin[w][8 * lane + 4] = E2.x; afin[w][8 * lane + 5] = O2.x;
  afin[w][8 * lane + 6] = E2.y; afin[w][8 * lane + 7] = O2.y;
  if (lane == 63) afin[w][512] = a8;
  cfinl[w][lane] = C;
  // dump and readout are wave-local: LDS ordering within a wave via lgkmcnt
  asm volatile("s_waitcnt lgkmcnt(0)" ::: "memory");
  if (lane == 0) {
    int s1 = 2 * tl, s2 = 2 * tl - 1;
    float v1 = afin[w][s1], v2 = afin[w][s2];
    int C1 = cfinl[w][s1 >= 512 ? 63 : (s1 >> 3)];
    int C2 = cfinl[w][s2 >= 512 ? 63 : (s2 >> 3)];
    float l1 = (v1 > 0.f) ? (log2_fast(v1) + (float)C1) : -1e30f;
    float l2 = (v2 > 0.f) ? (log2_fast(v2) + (float)C2) : -1e30f;
    float m  = fmaxf(l1, l2);
    float r  = m + log2_fast(exp2_fast(l1 - m) + exp2_fast(l2 - m));
    lossw[b] = -F_LN2 * (r + dsm);
  }
#undef STEP32
#undef RESCALE16
#undef ISSUE16
#undef BLK
}

// ---------------- zero_infinity guard, /tl, mean ----------------
__global__ __launch_bounds__(64) void k_final(const float* __restrict__ lossw,
                                              const int* __restrict__ tlen,
                                              float* __restrict__ out) {
  int i = threadIdx.x;
  float v = lossw[i];
  float d = (float)tlen[i];
  v = (v < 1e29f && v > -1e30f) ? (v / d) : 0.f;
  v += __shfl_xor(v, 1);
  v += __shfl_xor(v, 2);
  v += __shfl_xor(v, 4);
  v += __shfl_xor(v, 8);
  v += __shfl_xor(v, 16);
  v += __shfl_xor(v, 32);
  if (i == 0) out[0] = v * (1.f / BB);
}

extern "C" void kernel_launch(void* const* d_in, const int* in_sizes, int n_in,
                              void* d_out, int out_size, void* d_ws, size_t ws_size,
                              hipStream_t stream) {
  const float* lp = (const float*)d_in[0];
  const int* tgt  = (const int*)d_in[1];
  const int* ilen = (const int*)d_in[2];
  const int* tlen = (const int*)d_in[3];

  size_t eg_bytes = (size_t)BB * TT * SS * 2;          // 64 MB
  __half* Eg   = (__half*)d_ws;
  float* Bl    = (float*)((char*)d_ws + eg_bytes);     // [B][T]
  float* D2T   = Bl + (size_t)BB * TT;                 // [B][T]
  float* lossw = D2T + (size_t)BB * TT;                // [B]

  k_prep2<<<BB * (TT / 4), 256, 0, stream>>>(lp, tgt, Eg, Bl, D2T);
  k_ctc14<<<BB / WPB, 64 * WPB, 0, stream>>>(Eg, Bl, tgt, ilen, tlen, D2T, lossw);
  k_final<<<1, 64, 0, stream>>>(lossw, tlen, (float*)d_out);
}

// Round 18
// 136.977 us; speedup vs baseline: 1.4298x; 1.4298x over previous
//
#include <hip/hip_runtime.h>
#include <hip/hip_fp16.h>
#include <stdint.h>

// Problem constants (fixed by setup_inputs)
#define TT 2048
#define BB 64
#define VV 256
#define SS 256
#define LL 513

#define F_L2E 1.4426950408889634f
#define F_LN2 0.6931471805599453f
#define TGT_E 16   // per-lane rescale target: lane max -> [2^16, 2^17)
#define MARG  40   // max allowed C(i-1)-C(i)
#define KOFF  262144

typedef float f32x2 __attribute__((ext_vector_type(2)));

static __device__ __forceinline__ float exp2_fast(float x) {
  float r; asm("v_exp_f32 %0, %1" : "=v"(r) : "v"(x)); return r;
}
static __device__ __forceinline__ float log2_fast(float x) {
  float r; asm("v_log_f32 %0, %1" : "=v"(r) : "v"(x)); return r;
}
static __device__ __forceinline__ void g2l16(const void* g, void* l) {
  __builtin_amdgcn_global_load_lds((const __attribute__((address_space(1))) void*)g,
                                   (__attribute__((address_space(3))) void*)l, 16, 0, 0);
}
// wave_shr:1 — lane i gets lane i-1's value; lane 0 gets 0 (bound_ctrl). Pure VALU.
static __device__ __forceinline__ float dpp_shr1_f(float x) {
  int r = __builtin_amdgcn_update_dpp(0, __float_as_int(x), 0x138, 0xF, 0xF, true);
  return __int_as_float(r);
}
static __device__ __forceinline__ int dpp_shr1_i(int x) {
  return __builtin_amdgcn_update_dpp(0, x, 0x138, 0xF, 0xF, true);
}
// wave64 inclusive MAX-scan: shr1,2,4,8 (rmask F) + bcast15 (0xa) + bcast31 (0xc)
template <int CTRL, int RMASK>
static __device__ __forceinline__ int dppmax_i(int v) {
  int d = __builtin_amdgcn_update_dpp(v, v, CTRL, RMASK, 0xF, false);
  return v > d ? v : d;
}
static __device__ __forceinline__ int scanmax_i(int v) {
  v = dppmax_i<0x111, 0xF>(v);
  v = dppmax_i<0x112, 0xF>(v);
  v = dppmax_i<0x114, 0xF>(v);
  v = dppmax_i<0x118, 0xF>(v);
  v = dppmax_i<0x142, 0xa>(v);
  v = dppmax_i<0x143, 0xc>(v);
  return v;
}
// 2^d as f32, bit-built: exact for d in [-126,126]; 0 below; clamped above.
static __device__ __forceinline__ float pow2f(int d) {
  int dc = d > 126 ? 126 : d;
  float s = __int_as_float((dc + 127) << 23);
  return (d < -126) ? 0.f : s;
}

// ---------------------------------------------------------------------
// Phase 1: fused exp + row-sum + target-gather. (unchanged, at BW floor)
// ---------------------------------------------------------------------
__global__ __launch_bounds__(256) void k_prep2(const float* __restrict__ lp,
                                               const int* __restrict__ tgt,
                                               __half* __restrict__ Eg,
                                               float* __restrict__ Bl,
                                               float* __restrict__ D2T) {
  __shared__ int tgtl[SS];
  __shared__ __half elds[4][VV];
  int b  = blockIdx.x & (BB - 1);
  int t0 = (blockIdx.x >> 6) << 2;
  int tid = threadIdx.x;
  tgtl[tid] = tgt[b * SS + tid];
  __syncthreads();
  int w = tid >> 6, lane = tid & 63;
  int t = t0 + w;
  float4 x = reinterpret_cast<const float4*>(lp + ((size_t)t * BB + b) * VV)[lane];
  float e0 = exp2_fast(x.x * F_L2E), e1 = exp2_fast(x.y * F_L2E);
  float e2 = exp2_fast(x.z * F_L2E), e3 = exp2_fast(x.w * F_L2E);
  float z = (e0 + e1) + (e2 + e3);
  z += __shfl_xor(z, 1);
  z += __shfl_xor(z, 2);
  z += __shfl_xor(z, 4);
  z += __shfl_xor(z, 8);
  z += __shfl_xor(z, 16);
  z += __shfl_xor(z, 32);
  elds[w][4 * lane + 0] = __float2half_rn(e0);
  elds[w][4 * lane + 1] = __float2half_rn(e1);
  elds[w][4 * lane + 2] = __float2half_rn(e2);
  elds[w][4 * lane + 3] = __float2half_rn(e3);
  asm volatile("s_waitcnt lgkmcnt(0)" ::: "memory");   // wave-local write->read
  int s = 4 * lane;
  union { __half h[4]; uint2 u; } pk;
  pk.h[0] = elds[w][tgtl[s + 0]];
  pk.h[1] = elds[w][tgtl[s + 1]];
  pk.h[2] = elds[w][tgtl[s + 2]];
  pk.h[3] = elds[w][tgtl[s + 3]];
  reinterpret_cast<uint2*>(Eg + ((size_t)b * TT + t) * SS)[lane] = pk.u;
  if (lane == 0) {
    Bl[(size_t)b * TT + t]  = e0;
    D2T[(size_t)b * TT + t] = -log2_fast(z);
  }
}

// ---------------------------------------------------------------------
// Phase 2: f32 CTC DP, packed f32x2 cells, per-lane block exponent +
// margin clamp, 16-step rescale cadence. (R16 verbatim — best measured)
// ---------------------------------------------------------------------
__global__ __launch_bounds__(64) void k_ctc13(const __half* __restrict__ Eg,
                                              const float* __restrict__ Bl,
                                              const int* __restrict__ tgt,
                                              const int* __restrict__ ilen,
                                              const int* __restrict__ tlen,
                                              const float* __restrict__ D2T,
                                              float* __restrict__ lossw) {
  __shared__ float blanklds[TT];   // 8 KB
  __shared__ float afin[LL];
  __shared__ int   cfinl[64];
  int b = blockIdx.x, lane = threadIdx.x;
  int len = ilen[b]; if (len > TT) len = TT; if (len < 0) len = 0;
  int tl  = tlen[b]; if (tl > SS) tl = SS; if (tl < 1) tl = 1;

  const float* blb = Bl  + (size_t)b * TT;
  const float* d2b = D2T + (size_t)b * TT;
  const uint2* eq  = reinterpret_cast<const uint2*>(Eg) + (size_t)b * TT * 64 + lane;

  int4 tv = reinterpret_cast<const int4*>(tgt + b * SS)[lane];
  int pw  = __shfl_up(tv.w, 1);
  f32x2 mk13 = { (lane > 0 && tv.x != pw) ? 1.f : 0.f,
                 (tv.y != tv.x) ? 1.f : 0.f };
  f32x2 mk57 = { (tv.z != tv.y) ? 1.f : 0.f,
                 (tv.w != tv.z) ? 1.f : 0.f };

  // stage blank column (8 KB) into LDS
#pragma unroll
  for (int j = 0; j < 8; ++j)
    g2l16(blb + j * 256 + lane * 4, &blanklds[j * 256]);

  uint2 pfA[16], pfB[16], pfC[16];
  // E={a0,a2} O={a1,a3} E2={a4,a6} O2={a5,a7}, a8 scalar
  f32x2 E  = { (lane == 0) ? 1.f : 0.f, 0.f };
  f32x2 O  = { 0.f, 0.f };
  f32x2 E2 = { 0.f, 0.f };
  f32x2 O2 = { 0.f, 0.f };
  float a8 = 0.f;
  int   C = 0;          // per-lane block exponent (log2 units)
  float sc1f = 1.f;     // 2^{C(lane-1)-C(lane)} (bit-built), per rescale

#define ISSUE16(BANK, TBN) do {                                                \
    const uint2* p_ = eq + (size_t)(TBN) * 64;                                 \
    _Pragma("unroll")                                                          \
    for (int j_ = 0; j_ < 16; ++j_) pf##BANK[j_] = p_[(size_t)j_ * 64];        \
  } while (0)

#define STEP32(BANK, J) do {                                                   \
    uint2 pv = pf##BANK[J];                                                    \
    float2 tlo = __half22float2(*reinterpret_cast<const __half2*>(&pv.x));     \
    float2 thi = __half22float2(*reinterpret_cast<const __half2*>(&pv.y));     \
    f32x2 flo = { tlo.x, tlo.y };                                              \
    f32x2 fhi = { thi.x, thi.y };                                              \
    float pb = pbreg[J];                                                       \
    f32x2 pbv = { pb, pb };                                                    \
    float h1 = dpp_shr1_f(O2.y) * sc1f;                                        \
    f32x2 Av = { h1,  O.x  };                                                  \
    f32x2 Bv = { O.y, O2.x };                                                  \
    float a8n  = (a8 + O2.y) * pb;                                             \
    f32x2 En   = (E  + Av) * pbv;                                              \
    f32x2 E2n  = (E2 + Bv) * pbv;                                              \
    f32x2 On   = (O  + E  + mk13 * Av) * flo;                                  \
    f32x2 O2n  = (O2 + E2 + mk57 * Bv) * fhi;                                  \
    E = En; E2 = E2n; O = On; O2 = O2n; a8 = a8n;                              \
  } while (0)

  // Per-lane rescale with margin clamp; packed max-tree; 16-step cadence.
#define RESCALE16() do {                                                       \
    f32x2 m2 = __builtin_elementwise_max(__builtin_elementwise_max(E, O),      \
                                         __builtin_elementwise_max(E2, O2));   \
    float mx = fmaxf(fmaxf(m2.x, m2.y), a8);                                   \
    bool live_ = (mx > 0.f);                                                   \
    int e_  = (int)((__float_as_uint(mx) >> 23) & 0xff);                       \
    int Cl_ = C + e_ - (127 + TGT_E);                                          \
    int key_ = live_ ? (Cl_ + KOFF) : 0;                                       \
    key_ = scanmax_i(key_);                                                    \
    int Cn_ = (key_ - KOFF) - MARG;                                            \
    if (live_ && Cl_ > Cn_) Cn_ = Cl_;                                         \
    int shE_ = Cn_ - C;                                                        \
    E.x  = ldexpf(E.x, -shE_);  E.y  = ldexpf(E.y, -shE_);                     \
    O.x  = ldexpf(O.x, -shE_);  O.y  = ldexpf(O.y, -shE_);                     \
    E2.x = ldexpf(E2.x, -shE_); E2.y = ldexpf(E2.y, -shE_);                    \
    O2.x = ldexpf(O2.x, -shE_); O2.y = ldexpf(O2.y, -shE_);                    \
    a8   = ldexpf(a8, -shE_);                                                  \
    C = Cn_;                                                                   \
    int diffi_ = dpp_shr1_i(C) - C;                                            \
    sc1f = pow2f(diffi_);                                                      \
  } while (0)

#define BLK(CUR, NXT, TB, VMC) do {                                            \
    if ((VMC) == 32) ISSUE16(NXT, (TB) + 32);                                  \
    float pbreg[16];                                                           \
    _Pragma("unroll")                                                          \
    for (int j_ = 0; j_ < 16; ++j_) pbreg[j_] = blanklds[(TB) + j_];           \
    asm volatile("s_waitcnt vmcnt(%0)" :: "i"(VMC) : "memory");                \
    STEP32(CUR, 0);  STEP32(CUR, 1);  STEP32(CUR, 2);  STEP32(CUR, 3);         \
    STEP32(CUR, 4);  STEP32(CUR, 5);  STEP32(CUR, 6);  STEP32(CUR, 7);         \
    STEP32(CUR, 8);  STEP32(CUR, 9);  STEP32(CUR, 10); STEP32(CUR, 11);        \
    STEP32(CUR, 12); STEP32(CUR, 13); STEP32(CUR, 14); STEP32(CUR, 15);        \
    RESCALE16();                                                               \
  } while (0)

  int tcur = 0;
  if (len == TT) {
    ISSUE16(A, 0);
    ISSUE16(B, 16);
    for (int g = 0; g < 42; ++g) {
      BLK(A, C, tcur, 32);
      BLK(B, A, tcur + 16, 32);
      BLK(C, B, tcur + 32, 32);
      tcur += 48;
    }
    BLK(A, C, tcur, 16);       // tcur = 2016
    BLK(B, C, tcur + 16, 0);   // 2032
    tcur = TT;
  }

  // generic path (len < TT): plain per-step loads, same numerics
  if (tcur < len) {
    asm volatile("s_waitcnt vmcnt(0)" ::: "memory");
    while (tcur < len) {
      uint2 pv = eq[(size_t)tcur * 64];
      float2 tlo = __half22float2(*reinterpret_cast<const __half2*>(&pv.x));
      float2 thi = __half22float2(*reinterpret_cast<const __half2*>(&pv.y));
      f32x2 flo = { tlo.x, tlo.y };
      f32x2 fhi = { thi.x, thi.y };
      float pb = blanklds[tcur];
      f32x2 pbv = { pb, pb };
      float h1 = dpp_shr1_f(O2.y) * sc1f;
      f32x2 Av = { h1,  O.x  };
      f32x2 Bv = { O.y, O2.x };
      float a8n  = (a8 + O2.y) * pb;
      f32x2 En   = (E  + Av) * pbv;
      f32x2 E2n  = (E2 + Bv) * pbv;
      f32x2 On   = (O  + E  + mk13 * Av) * flo;
      f32x2 O2n  = (O2 + E2 + mk57 * Bv) * fhi;
      E = En; E2 = E2n; O = On; O2 = O2n; a8 = a8n;
      ++tcur;
      if ((tcur & 15) == 0) RESCALE16();
    }
  }

  // normalization constant: sum of -log2(Z_t) over t < len
  float dsm = 0.f;
  for (int k2 = 0; k2 < TT / 64; ++k2) {
    int t2 = lane + 64 * k2;
    if (t2 < len) dsm += d2b[t2];
  }
  dsm += __shfl_xor(dsm, 1);
  dsm += __shfl_xor(dsm, 2);
  dsm += __shfl_xor(dsm, 4);
  dsm += __shfl_xor(dsm, 8);
  dsm += __shfl_xor(dsm, 16);
  dsm += __shfl_xor(dsm, 32);

  // cells: a0=E.x a1=O.x a2=E.y a3=O.y a4=E2.x a5=O2.x a6=E2.y a7=O2.y
  afin[8 * lane + 0] = E.x;  afin[8 * lane + 1] = O.x;
  afin[8 * lane + 2] = E.y;  afin[8 * lane + 3] = O.y;
  afin[8 * lane + 4] = E2.x; afin[8 * lane + 5] = O2.x;
  afin[8 * lane + 6] = E2.y; afin[8 * lane + 7] = O2.y;
  if (lane == 63) afin[512] = a8;
  cfinl[lane] = C;
  __syncthreads();
  if (lane == 0) {
    int s1 = 2 * tl, s2 = 2 * tl - 1;
    float v1 = afin[s1], v2 = afin[s2];
    int C1 = cfinl[s1 >= 512 ? 63 : (s1 >> 3)];
    int C2 = cfinl[s2 >= 512 ? 63 : (s2 >> 3)];
    float l1 = (v1 > 0.f) ? (log2_fast(v1) + (float)C1) : -1e30f;
    float l2 = (v2 > 0.f) ? (log2_fast(v2) + (float)C2) : -1e30f;
    float m  = fmaxf(l1, l2);
    float r  = m + log2_fast(exp2_fast(l1 - m) + exp2_fast(l2 - m));
    lossw[b] = -F_LN2 * (r + dsm);
  }
#undef STEP32
#undef RESCALE16
#undef ISSUE16
#undef BLK
}

// ---------------- zero_infinity guard, /tl, mean ----------------
__global__ __launch_bounds__(64) void k_final(const float* __restrict__ lossw,
                                              const int* __restrict__ tlen,
                                              float* __restrict__ out) {
  int i = threadIdx.x;
  float v = lossw[i];
  float d = (float)tlen[i];
  v = (v < 1e29f && v > -1e30f) ? (v / d) : 0.f;
  v += __shfl_xor(v, 1);
  v += __shfl_xor(v, 2);
  v += __shfl_xor(v, 4);
  v += __shfl_xor(v, 8);
  v += __shfl_xor(v, 16);
  v += __shfl_xor(v, 32);
  if (i == 0) out[0] = v * (1.f / BB);
}

extern "C" void kernel_launch(void* const* d_in, const int* in_sizes, int n_in,
                              void* d_out, int out_size, void* d_ws, size_t ws_size,
                              hipStream_t stream) {
  const float* lp = (const float*)d_in[0];
  const int* tgt  = (const int*)d_in[1];
  const int* ilen = (const int*)d_in[2];
  const int* tlen = (const int*)d_in[3];

  size_t eg_bytes = (size_t)BB * TT * SS * 2;          // 64 MB
  __half* Eg   = (__half*)d_ws;
  float* Bl    = (float*)((char*)d_ws + eg_bytes);     // [B][T]
  float* D2T   = Bl + (size_t)BB * TT;                 // [B][T]
  float* lossw = D2T + (size_t)BB * TT;                // [B]

  k_prep2<<<BB * (TT / 4), 256, 0, stream>>>(lp, tgt, Eg, Bl, D2T);
  k_ctc13<<<BB, 64, 0, stream>>>(Eg, Bl, tgt, ilen, tlen, D2T, lossw);
  k_final<<<1, 64, 0, stream>>>(lossw, tlen, (float*)d_out);
}